// Round 6
// baseline (455.467 us; speedup 1.0000x reference)
//
#include <hip/hip_runtime.h>
#include <stdint.h>

#define ROWLEN 4096
#define KSEL   1024
#define NTHREADS 256
#define NBINS  2048      // 11-bit digit = v >> 21
#define KEYCAP 1536      // < 1024 above-boundary + <=512 boundary group
#define GLCAP  256
typedef unsigned long long u64;

// Monotonic float->uint map: order(f) preserved as unsigned compare.
__device__ __forceinline__ uint32_t f2u_sortable(float f) {
    uint32_t u = __float_as_uint(f);
    return u ^ ((int32_t)u < 0 ? 0xFFFFFFFFu : 0x80000000u);
}

__device__ __forceinline__ void cmpex(u64 &a, u64 &b, bool maxFirst) {
    u64 lo = a < b ? a : b;
    u64 hi = a < b ? b : a;
    a = maxFirst ? hi : lo;
    b = maxFirst ? lo : hi;
}

// Full descending bitonic sort of P=2^LOGP keys held by one wave,
// element i = lane + 64*e. j<64 via shfl_xor, j>=64 in-register. No LDS.
template<int LOGP>
__device__ __forceinline__ void wave_bitonic_desc(u64 r[], int lane) {
    constexpr int P = 1 << LOGP;
    constexpr int E = (P > 64) ? (P / 64) : 1;
#pragma unroll
    for (int k = 2; k <= P; k <<= 1) {
#pragma unroll
        for (int j = k >> 1; j > 0; j >>= 1) {
            if (j >= 64) {
                const int jr = j >> 6;
#pragma unroll
                for (int e = 0; e < E; ++e) {
                    if ((e & jr) == 0) {
                        int il = lane + 64 * e;
                        cmpex(r[e], r[e | jr], (il & k) == 0);
                    }
                }
            } else {
#pragma unroll
                for (int e = 0; e < E; ++e) {
                    u64 o = __shfl_xor(r[e], j, 64);
                    int i = lane + 64 * e;
                    bool takeMax = (((i & j) == 0) == ((i & k) == 0));
                    r[e] = ((r[e] > o) == takeMax) ? r[e] : o;   // keys distinct
                }
            }
        }
    }
}

__global__ __launch_bounds__(NTHREADS, 8) void adaptive_topk_kernel(
    const float* __restrict__ in, int* __restrict__ out_idx, int* __restrict__ out_k)
{
    __shared__ uint32_t A32[NBINS / 2];   // packed u16 bins: hist -> suffix-excl -> cursors
    __shared__ u64 keys[KEYCAP];          // 12 KB grouped scatter buffer
    __shared__ uint16_t outbuf[KSEL];     // 2 KB sorted indices staging
    __shared__ uint32_t glist[GLCAP];     // (n<<16)|base per active group
    __shared__ uint32_t wavetot[4];
    __shared__ float wsum[4], wsum2[4];
    __shared__ int sh_d1, sh_ng, sh_gp, sh_fb;

    const int row  = blockIdx.x;
    const int tid  = threadIdx.x;
    const int lane = tid & 63;
    const int wv   = tid >> 6;
    const float* __restrict__ rowp = in + (size_t)row * ROWLEN;
    int* __restrict__ orow = out_idx + (size_t)row * KSEL;

    const uint4 z0 = {0u, 0u, 0u, 0u};
    ((uint4*)A32)[tid] = z0;              // clear 1024 words = 2048 u16 bins
    if (tid == 0) { sh_ng = 0; sh_gp = 0; sh_fb = 0; }
    __syncthreads();

    // ---- load row into REGISTERS + 11-bit histogram (packed u16) + moments ----
    uint4 w[4];                            // elem idx = 4*(tid + 256*it) + e
    float s = 0.0f, s2 = 0.0f;
    const float4* r4 = (const float4*)rowp;
#pragma unroll
    for (int it = 0; it < 4; ++it) {
        float4 v = r4[tid + 256 * it];
        s += (v.x + v.y) + (v.z + v.w);
        s2 = fmaf(v.x, v.x, fmaf(v.y, v.y, fmaf(v.z, v.z, fmaf(v.w, v.w, s2))));
        uint32_t ux = f2u_sortable(v.x), uy = f2u_sortable(v.y);
        uint32_t uz = f2u_sortable(v.z), uw = f2u_sortable(v.w);
        w[it].x = ux; w[it].y = uy; w[it].z = uz; w[it].w = uw;
        uint32_t bx = ux >> 21, by = uy >> 21, bz = uz >> 21, bw = uw >> 21;
        atomicAdd(&A32[bx >> 1], (bx & 1) ? (1u << 16) : 1u);
        atomicAdd(&A32[by >> 1], (by & 1) ? (1u << 16) : 1u);
        atomicAdd(&A32[bz >> 1], (bz & 1) ? (1u << 16) : 1u);
        atomicAdd(&A32[bw >> 1], (bw & 1) ? (1u << 16) : 1u);
    }
    for (int off = 32; off > 0; off >>= 1) {
        s  += __shfl_down(s, off);
        s2 += __shfl_down(s2, off);
    }
    if (lane == 0) { wsum[wv] = s; wsum2[wv] = s2; }
    __syncthreads();                      // hist + wsum complete
    if (tid == 0) {
        double S  = (double)wsum[0] + wsum[1] + wsum[2] + wsum[3];
        double S2 = (double)wsum2[0] + wsum2[1] + wsum2[2] + wsum2[3];
        double var = (S2 - S * S / (double)ROWLEN) / (double)(ROWLEN - 1);
        float sp = log1pf(expf((float)var));
        float ka = 512.0f * (1.0f + 0.1f * sp);
        ka = fminf(fmaxf(ka, 128.0f), 1024.0f);
        out_k[row] = (int)ka;
    }

    // ---- in-place EXCLUSIVE suffix scan over bins (A[g] := #elems in bins > g),
    //      fused with boundary-digit detection ----
    uint4 hw = ((uint4*)A32)[tid];        // my 8 bins (4 words)
    uint32_t cnt[8] = { hw.x & 0xFFFFu, hw.x >> 16, hw.y & 0xFFFFu, hw.y >> 16,
                        hw.z & 0xFFFFu, hw.z >> 16, hw.w & 0xFFFFu, hw.w >> 16 };
    uint32_t csum = 0;
#pragma unroll
    for (int b = 0; b < 8; ++b) csum += cnt[b];
    uint32_t incl = csum;                 // inclusive suffix over chunk sums in wave
#pragma unroll
    for (int off = 1; off < 64; off <<= 1) {
        uint32_t t = __shfl_down(incl, off);
        if (lane + off < 64) incl += t;
    }
    if (lane == 0) wavetot[wv] = incl;
    __syncthreads();
    uint32_t later = 0;
    for (int w2 = wv + 1; w2 < 4; ++w2) later += wavetot[w2];
    uint32_t run = (incl - csum) + later; // elems in bins after my chunk
    uint32_t runs[8];
#pragma unroll
    for (int b = 7; b >= 0; --b) {
        uint32_t h = cnt[b];
        if (run < KSEL && KSEL <= run + h) sh_d1 = 8 * tid + b;
        runs[b] = run;                    // exclusive suffix for bin 8*tid+b
        run += h;
    }
    uint4 ww;
    ww.x = runs[0] | (runs[1] << 16);
    ww.y = runs[2] | (runs[3] << 16);
    ww.z = runs[4] | (runs[5] << 16);
    ww.w = runs[6] | (runs[7] << 16);
    ((uint4*)A32)[tid] = ww;
    __syncthreads();                      // A = bases, sh_d1 visible

    const int d1 = sh_d1;

    // ---- group list build (from regs) + grouped scatter (cursors = A halves) ----
#pragma unroll
    for (int b = 0; b < 8; ++b) {
        int g = 8 * tid + b;
        uint32_t n = cnt[b];
        if (g >= d1 && n > 0) {
            if (n > 512) sh_fb = 1;
            int p = atomicAdd(&sh_ng, 1);
            if (p < GLCAP) glist[p] = (n << 16) | runs[b];
            else sh_fb = 1;
        }
    }
#pragma unroll
    for (int it = 0; it < 4; ++it) {
        uint32_t vv[4] = { w[it].x, w[it].y, w[it].z, w[it].w };
#pragma unroll
        for (int e = 0; e < 4; ++e) {
            uint32_t u = vv[e];
            int g = (int)(u >> 21);
            if (g >= d1) {
                uint32_t old = atomicAdd(&A32[g >> 1], (g & 1) ? (1u << 16) : 1u);
                uint32_t pos = (g & 1) ? (old >> 16) : (old & 0xFFFFu);
                int idx = 4 * (tid + 256 * it) + e;
                if (pos < KEYCAP)
                    keys[pos] = ((u64)u << 12) | (u64)(ROWLEN - 1 - idx);
            }
        }
    }
    __syncthreads();                      // keys + glist complete

    const int ng = min(sh_ng, GLCAP);
    if (!sh_fb) {
        // ---- per-group in-wave sorts -> LDS outbuf (no barriers, dyn balance) ----
#define GROUP_SORT(LOGP, EE)                                                  \
        {                                                                     \
            u64 rr[EE];                                                       \
            _Pragma("unroll")                                                 \
            for (int e = 0; e < EE; ++e) {                                    \
                int i = lane + 64 * e;                                        \
                rr[e] = (i < n) ? keys[base + i] : 0ull;                      \
            }                                                                 \
            wave_bitonic_desc<LOGP>(rr, lane);                                \
            _Pragma("unroll")                                                 \
            for (int e = 0; e < EE; ++e) {                                    \
                int i = lane + 64 * e;                                        \
                if (i < quota)                                                \
                    outbuf[base + i] =                                        \
                        (uint16_t)((ROWLEN - 1) - (int)(rr[e] & 0xFFFu));     \
            }                                                                 \
        }
        for (;;) {
            int gi = 0;
            if (lane == 0) gi = atomicAdd(&sh_gp, 1);
            gi = __shfl(gi, 0);
            if (gi >= ng) break;
            uint32_t ent = glist[gi];
            int base  = (int)(ent & 0xFFFFu);
            int n     = (int)(ent >> 16);
            int quota = min(n, KSEL - base);
            if (n <= 64)       GROUP_SORT(6, 1)
            else if (n <= 128) GROUP_SORT(7, 2)
            else if (n <= 256) GROUP_SORT(8, 4)
            else               GROUP_SORT(9, 8)
        }
#undef GROUP_SORT
        __syncthreads();                  // outbuf complete
        // ---- single coalesced row store: ushort4 (LDS) -> int4 (global) ----
        ushort4 t4 = ((const ushort4*)outbuf)[tid];
        int4 ov = { (int)t4.x, (int)t4.y, (int)t4.z, (int)t4.w };
        ((int4*)orow)[tid] = ov;
    } else {
        // ---- exact cooperative fallback (statistically never taken) ----
        if (tid < 64) {
            u64 prev = ~0ull;
            for (int r = 0; r < KSEL; ++r) {
                u64 best = 0;
                for (int c = lane; c < ROWLEN; c += 64) {
                    u64 K = ((u64)f2u_sortable(rowp[c]) << 12) | (u64)(ROWLEN - 1 - c);
                    if (K < prev && K > best) best = K;
                }
                for (int off = 32; off > 0; off >>= 1) {
                    u64 o = __shfl_xor(best, off, 64);
                    best = best > o ? best : o;
                }
                if (lane == 0) orow[r] = (ROWLEN - 1) - (int)(best & 0xFFFu);
                prev = best;
            }
        }
    }
}

extern "C" void kernel_launch(void* const* d_in, const int* in_sizes, int n_in,
                              void* d_out, int out_size, void* d_ws, size_t ws_size,
                              hipStream_t stream) {
    const float* in = (const float*)d_in[0];
    const int B = in_sizes[0] / (ROWLEN * ROWLEN);   // 4
    const int nrows = B * ROWLEN;                    // 16384
    int* out = (int*)d_out;
    int* out_idx = out;                              // B*L*KSEL
    int* out_k   = out + (size_t)nrows * KSEL;       // B*L
    adaptive_topk_kernel<<<dim3(nrows), dim3(NTHREADS), 0, stream>>>(in, out_idx, out_k);
}

// Round 7
// 319.385 us; speedup vs baseline: 1.4261x; 1.4261x over previous
//
#include <hip/hip_runtime.h>
#include <stdint.h>

#define ROWLEN 4096
#define KSEL   1024
#define NTHREADS 256
#define NBINS  4096      // 12-bit digit = v >> 20
#define KEYCAP 1536
#define GLCAP  256
typedef unsigned long long u64;

// Monotonic float->uint map: order(f) preserved as unsigned compare.
__device__ __forceinline__ uint32_t f2u_sortable(float f) {
    uint32_t u = __float_as_uint(f);
    return u ^ ((int32_t)u < 0 ? 0xFFFFFFFFu : 0x80000000u);
}

// One bitonic exchange via lane shuffle; i = global element index of this reg.
__device__ __forceinline__ uint32_t shstage(uint32_t r, int i, int j, int k) {
    uint32_t o = __shfl_xor(r, j, 64);
    bool takeMax = (((i & j) == 0) == ((i & k) == 0));
    return ((r > o) == takeMax) ? r : o;   // keys distinct
}
__device__ __forceinline__ void cmpex32(uint32_t &a, uint32_t &b, bool maxFirst) {
    uint32_t lo = a < b ? a : b, hi = a < b ? b : a;
    a = maxFirst ? hi : lo;
    b = maxFirst ? lo : hi;
}

// Descending bitonic sorts, named scalars only (no arrays -> no scratch risk).
__device__ __forceinline__ void sort64d(uint32_t &r0, int lane) {
#pragma unroll
    for (int k = 2; k <= 64; k <<= 1)
#pragma unroll
        for (int j = k >> 1; j > 0; j >>= 1)
            r0 = shstage(r0, lane, j, k);
}
__device__ __forceinline__ void sort128d(uint32_t &r0, uint32_t &r1, int lane) {
    const int i0 = lane, i1 = lane + 64;
#pragma unroll
    for (int k = 2; k <= 64; k <<= 1)
#pragma unroll
        for (int j = k >> 1; j > 0; j >>= 1) {
            r0 = shstage(r0, i0, j, k);
            r1 = shstage(r1, i1, j, k);
        }
    cmpex32(r0, r1, true);                 // k=128, j=64
#pragma unroll
    for (int j = 32; j > 0; j >>= 1) {
        r0 = shstage(r0, i0, j, 128);
        r1 = shstage(r1, i1, j, 128);
    }
}
__device__ __forceinline__ void sort256d(uint32_t &r0, uint32_t &r1,
                                         uint32_t &r2, uint32_t &r3, int lane) {
    const int i0 = lane, i1 = lane + 64, i2 = lane + 128, i3 = lane + 192;
#pragma unroll
    for (int k = 2; k <= 64; k <<= 1)
#pragma unroll
        for (int j = k >> 1; j > 0; j >>= 1) {
            r0 = shstage(r0, i0, j, k);
            r1 = shstage(r1, i1, j, k);
            r2 = shstage(r2, i2, j, k);
            r3 = shstage(r3, i3, j, k);
        }
    cmpex32(r0, r1, true);                 // k=128, j=64
    cmpex32(r2, r3, false);
#pragma unroll
    for (int j = 32; j > 0; j >>= 1) {
        r0 = shstage(r0, i0, j, 128);
        r1 = shstage(r1, i1, j, 128);
        r2 = shstage(r2, i2, j, 128);
        r3 = shstage(r3, i3, j, 128);
    }
    cmpex32(r0, r2, true); cmpex32(r1, r3, true);   // k=256, j=128
    cmpex32(r0, r1, true); cmpex32(r2, r3, true);   // k=256, j=64
#pragma unroll
    for (int j = 32; j > 0; j >>= 1) {
        r0 = shstage(r0, i0, j, 256);
        r1 = shstage(r1, i1, j, 256);
        r2 = shstage(r2, i2, j, 256);
        r3 = shstage(r3, i3, j, 256);
    }
}

__global__ __launch_bounds__(NTHREADS, 8) void adaptive_topk_kernel(
    const float* __restrict__ in, int* __restrict__ out_idx, int* __restrict__ out_k)
{
    __shared__ uint32_t A32[NBINS / 2];   // 8 KB packed u16 bins: hist -> bases/cursors
    __shared__ uint32_t keys[KEYCAP];     // 6 KB u32 group-scatter keys
    __shared__ uint16_t outbuf[KSEL];     // 2 KB sorted indices staging
    __shared__ uint32_t glist[GLCAP];     // (n<<16)|base per active group
    __shared__ uint32_t wavetot[4];
    __shared__ float wsum[4], wsum2[4];
    __shared__ int sh_d1, sh_ng, sh_gp, sh_fb;

    const int row  = blockIdx.x;
    const int tid  = threadIdx.x;
    const int lane = tid & 63;
    const int wv   = tid >> 6;
    const float* __restrict__ rowp = in + (size_t)row * ROWLEN;
    int* __restrict__ orow = out_idx + (size_t)row * KSEL;

    const uint4 z0 = {0u, 0u, 0u, 0u};
    ((uint4*)A32)[tid] = z0;              // clear 2048 words (4096 u16 bins)
    ((uint4*)A32)[tid + 256] = z0;
    if (tid == 0) { sh_ng = 0; sh_gp = 0; sh_fb = 0; }
    __syncthreads();

    // ---- load row into REGISTERS + 12-bit histogram (packed u16) + moments ----
    uint4 w[4];                            // elem idx = 4*(tid + 256*it) + e
    float s = 0.0f, s2 = 0.0f;
    const float4* r4 = (const float4*)rowp;
#pragma unroll
    for (int it = 0; it < 4; ++it) {
        float4 v = r4[tid + 256 * it];
        s += (v.x + v.y) + (v.z + v.w);
        s2 = fmaf(v.x, v.x, fmaf(v.y, v.y, fmaf(v.z, v.z, fmaf(v.w, v.w, s2))));
        uint32_t ux = f2u_sortable(v.x), uy = f2u_sortable(v.y);
        uint32_t uz = f2u_sortable(v.z), uw = f2u_sortable(v.w);
        w[it].x = ux; w[it].y = uy; w[it].z = uz; w[it].w = uw;
        uint32_t bx = ux >> 20, by = uy >> 20, bz = uz >> 20, bw = uw >> 20;
        atomicAdd(&A32[bx >> 1], (bx & 1) ? (1u << 16) : 1u);
        atomicAdd(&A32[by >> 1], (by & 1) ? (1u << 16) : 1u);
        atomicAdd(&A32[bz >> 1], (bz & 1) ? (1u << 16) : 1u);
        atomicAdd(&A32[bw >> 1], (bw & 1) ? (1u << 16) : 1u);
    }
    for (int off = 32; off > 0; off >>= 1) {
        s  += __shfl_down(s, off);
        s2 += __shfl_down(s2, off);
    }
    if (lane == 0) { wsum[wv] = s; wsum2[wv] = s2; }
    __syncthreads();                      // hist + wsum complete
    if (tid == 0) {
        double S  = (double)wsum[0] + wsum[1] + wsum[2] + wsum[3];
        double S2 = (double)wsum2[0] + wsum2[1] + wsum2[2] + wsum2[3];
        double var = (S2 - S * S / (double)ROWLEN) / (double)(ROWLEN - 1);
        float sp = log1pf(expf((float)var));
        float ka = 512.0f * (1.0f + 0.1f * sp);
        ka = fminf(fmaxf(ka, 128.0f), 1024.0f);
        out_k[row] = (int)ka;
    }

    // ---- suffix scan over 4096 bins; find boundary digit d1; store bases ----
    uint32_t hww[8];                       // my 16 bins, packed (8 words)
    {
        uint4 h0 = ((uint4*)A32)[2 * tid];
        uint4 h1 = ((uint4*)A32)[2 * tid + 1];
        hww[0] = h0.x; hww[1] = h0.y; hww[2] = h0.z; hww[3] = h0.w;
        hww[4] = h1.x; hww[5] = h1.y; hww[6] = h1.z; hww[7] = h1.w;
    }
    uint32_t csum = 0;
#pragma unroll
    for (int q = 0; q < 8; ++q) csum += (hww[q] & 0xFFFFu) + (hww[q] >> 16);
    uint32_t incl = csum;                 // inclusive suffix over chunk sums in wave
#pragma unroll
    for (int off = 1; off < 64; off <<= 1) {
        uint32_t t = __shfl_down(incl, off);
        if (lane + off < 64) incl += t;
    }
    if (lane == 0) wavetot[wv] = incl;
    __syncthreads();
    uint32_t later = 0;
    for (int w2 = wv + 1; w2 < 4; ++w2) later += wavetot[w2];
    const uint32_t R = (incl - csum) + later;   // elems in bins after my chunk
    {
        uint32_t run = R;
        uint32_t packed[8];
#pragma unroll
        for (int b = 15; b >= 0; --b) {
            uint32_t h = (hww[b >> 1] >> ((b & 1) * 16)) & 0xFFFFu;
            if (run < KSEL && KSEL <= run + h) sh_d1 = 16 * tid + b;
            if (b & 1) packed[b >> 1] = run << 16;
            else       packed[b >> 1] |= run;
            run += h;
        }
        uint4 p0 = { packed[0], packed[1], packed[2], packed[3] };
        uint4 p1 = { packed[4], packed[5], packed[6], packed[7] };
        ((uint4*)A32)[2 * tid] = p0;      // own-slot rewrite, no cross-thread dep
        ((uint4*)A32)[2 * tid + 1] = p1;
    }
    __syncthreads();                      // bases + sh_d1 visible

    const int d1 = sh_d1;

    // ---- group list build (bases recomputed by running subtraction) ----
    {
        uint32_t run2 = R + csum;
#pragma unroll
        for (int b = 0; b < 16; ++b) {
            uint32_t n = (hww[b >> 1] >> ((b & 1) * 16)) & 0xFFFFu;
            run2 -= n;                    // = base of bin g
            int g = 16 * tid + b;
            if (g >= d1 && n > 0) {
                if (n > 256) sh_fb = 1;
                int p = atomicAdd(&sh_ng, 1);
                if (p < GLCAP) glist[p] = (n << 16) | run2;
                else sh_fb = 1;
            }
        }
    }
    // ---- grouped scatter (cursors = A32 u16 halves), u32 keys ----
#pragma unroll
    for (int it = 0; it < 4; ++it) {
        uint32_t vv[4] = { w[it].x, w[it].y, w[it].z, w[it].w };
#pragma unroll
        for (int e = 0; e < 4; ++e) {
            uint32_t u = vv[e];
            int g = (int)(u >> 20);
            if (g >= d1) {
                uint32_t old = atomicAdd(&A32[g >> 1], (g & 1) ? (1u << 16) : 1u);
                uint32_t pos = (g & 1) ? (old >> 16) : (old & 0xFFFFu);
                int idx = 4 * (tid + 256 * it) + e;
                if (pos < KEYCAP)
                    keys[pos] = (u << 12) | (uint32_t)(ROWLEN - 1 - idx);
            }
        }
    }
    __syncthreads();                      // keys + glist complete

    const int ng = min(sh_ng, GLCAP);
    if (!sh_fb) {
        // ---- per-group in-wave sorts -> LDS outbuf (no barriers) ----
        for (;;) {
            int gi = 0;
            if (lane == 0) gi = atomicAdd(&sh_gp, 1);
            gi = __shfl(gi, 0);
            if (gi >= ng) break;
            uint32_t ent = glist[gi];
            int base  = (int)(ent & 0xFFFFu);
            int n     = (int)(ent >> 16);
            int quota = min(n, KSEL - base);
            const int i0 = lane, i1 = lane + 64, i2 = lane + 128, i3 = lane + 192;
            if (n <= 64) {
                uint32_t r0 = (i0 < n) ? keys[base + i0] : 0u;
                sort64d(r0, lane);
                if (i0 < quota)
                    outbuf[base + i0] = (uint16_t)((ROWLEN - 1) - (int)(r0 & 0xFFFu));
            } else if (n <= 128) {
                uint32_t r0 = (i0 < n) ? keys[base + i0] : 0u;
                uint32_t r1 = (i1 < n) ? keys[base + i1] : 0u;
                sort128d(r0, r1, lane);
                if (i0 < quota)
                    outbuf[base + i0] = (uint16_t)((ROWLEN - 1) - (int)(r0 & 0xFFFu));
                if (i1 < quota)
                    outbuf[base + i1] = (uint16_t)((ROWLEN - 1) - (int)(r1 & 0xFFFu));
            } else {
                uint32_t r0 = (i0 < n) ? keys[base + i0] : 0u;
                uint32_t r1 = (i1 < n) ? keys[base + i1] : 0u;
                uint32_t r2 = (i2 < n) ? keys[base + i2] : 0u;
                uint32_t r3 = (i3 < n) ? keys[base + i3] : 0u;
                sort256d(r0, r1, r2, r3, lane);
                if (i0 < quota)
                    outbuf[base + i0] = (uint16_t)((ROWLEN - 1) - (int)(r0 & 0xFFFu));
                if (i1 < quota)
                    outbuf[base + i1] = (uint16_t)((ROWLEN - 1) - (int)(r1 & 0xFFFu));
                if (i2 < quota)
                    outbuf[base + i2] = (uint16_t)((ROWLEN - 1) - (int)(r2 & 0xFFFu));
                if (i3 < quota)
                    outbuf[base + i3] = (uint16_t)((ROWLEN - 1) - (int)(r3 & 0xFFFu));
            }
        }
        __syncthreads();                  // outbuf complete
        // ---- single coalesced row store: ushort4 (LDS) -> int4 (global) ----
        ushort4 t4 = ((const ushort4*)outbuf)[tid];
        int4 ov = { (int)t4.x, (int)t4.y, (int)t4.z, (int)t4.w };
        ((int4*)orow)[tid] = ov;
    } else {
        // ---- exact cooperative fallback (statistically never taken) ----
        if (tid < 64) {
            u64 prev = ~0ull;
            for (int r = 0; r < KSEL; ++r) {
                u64 best = 0;
                for (int c = lane; c < ROWLEN; c += 64) {
                    u64 K = ((u64)f2u_sortable(rowp[c]) << 12) | (u64)(ROWLEN - 1 - c);
                    if (K < prev && K > best) best = K;
                }
                for (int off = 32; off > 0; off >>= 1) {
                    u64 o = __shfl_xor(best, off, 64);
                    best = best > o ? best : o;
                }
                if (lane == 0) orow[r] = (ROWLEN - 1) - (int)(best & 0xFFFu);
                prev = best;
            }
        }
    }
}

extern "C" void kernel_launch(void* const* d_in, const int* in_sizes, int n_in,
                              void* d_out, int out_size, void* d_ws, size_t ws_size,
                              hipStream_t stream) {
    const float* in = (const float*)d_in[0];
    const int B = in_sizes[0] / (ROWLEN * ROWLEN);   // 4
    const int nrows = B * ROWLEN;                    // 16384
    int* out = (int*)d_out;
    int* out_idx = out;                              // B*L*KSEL
    int* out_k   = out + (size_t)nrows * KSEL;       // B*L
    adaptive_topk_kernel<<<dim3(nrows), dim3(NTHREADS), 0, stream>>>(in, out_idx, out_k);
}

// Round 8
// 234.284 us; speedup vs baseline: 1.9441x; 1.3632x over previous
//
#include <hip/hip_runtime.h>
#include <stdint.h>

#define ROWLEN 4096
#define KSEL   1024
#define NTHREADS 256
#define NBINS  4096      // 12-bit digit = v >> 20
#define KEYCAP 1536
#define GLCAP  256
typedef unsigned long long u64;

// Monotonic float->uint map: order(f) preserved as unsigned compare.
__device__ __forceinline__ uint32_t f2u_sortable(float f) {
    uint32_t u = __float_as_uint(f);
    return u ^ ((int32_t)u < 0 ? 0xFFFFFFFFu : 0x80000000u);
}

// One bitonic exchange via lane shuffle; i = global element index of this reg.
__device__ __forceinline__ uint32_t shstage(uint32_t r, int i, int j, int k) {
    uint32_t o = __shfl_xor(r, j, 64);
    bool takeMax = (((i & j) == 0) == ((i & k) == 0));
    return ((r > o) == takeMax) ? r : o;   // keys distinct
}
__device__ __forceinline__ void cmpex32(uint32_t &a, uint32_t &b, bool maxFirst) {
    uint32_t lo = a < b ? a : b, hi = a < b ? b : a;
    a = maxFirst ? hi : lo;
    b = maxFirst ? lo : hi;
}

// Descending bitonic sorts, named scalars only (no arrays -> no scratch risk).
__device__ __forceinline__ void sort64d(uint32_t &r0, int lane) {
#pragma unroll
    for (int k = 2; k <= 64; k <<= 1)
#pragma unroll
        for (int j = k >> 1; j > 0; j >>= 1)
            r0 = shstage(r0, lane, j, k);
}
__device__ __forceinline__ void sort128d(uint32_t &r0, uint32_t &r1, int lane) {
    const int i0 = lane, i1 = lane + 64;
#pragma unroll
    for (int k = 2; k <= 64; k <<= 1)
#pragma unroll
        for (int j = k >> 1; j > 0; j >>= 1) {
            r0 = shstage(r0, i0, j, k);
            r1 = shstage(r1, i1, j, k);
        }
    cmpex32(r0, r1, true);                 // k=128, j=64
#pragma unroll
    for (int j = 32; j > 0; j >>= 1) {
        r0 = shstage(r0, i0, j, 128);
        r1 = shstage(r1, i1, j, 128);
    }
}
__device__ __forceinline__ void sort256d(uint32_t &r0, uint32_t &r1,
                                         uint32_t &r2, uint32_t &r3, int lane) {
    const int i0 = lane, i1 = lane + 64, i2 = lane + 128, i3 = lane + 192;
#pragma unroll
    for (int k = 2; k <= 64; k <<= 1)
#pragma unroll
        for (int j = k >> 1; j > 0; j >>= 1) {
            r0 = shstage(r0, i0, j, k);
            r1 = shstage(r1, i1, j, k);
            r2 = shstage(r2, i2, j, k);
            r3 = shstage(r3, i3, j, k);
        }
    cmpex32(r0, r1, true);                 // k=128, j=64
    cmpex32(r2, r3, false);
#pragma unroll
    for (int j = 32; j > 0; j >>= 1) {
        r0 = shstage(r0, i0, j, 128);
        r1 = shstage(r1, i1, j, 128);
        r2 = shstage(r2, i2, j, 128);
        r3 = shstage(r3, i3, j, 128);
    }
    cmpex32(r0, r2, true); cmpex32(r1, r3, true);   // k=256, j=128
    cmpex32(r0, r1, true); cmpex32(r2, r3, true);   // k=256, j=64
#pragma unroll
    for (int j = 32; j > 0; j >>= 1) {
        r0 = shstage(r0, i0, j, 256);
        r1 = shstage(r1, i1, j, 256);
        r2 = shstage(r2, i2, j, 256);
        r3 = shstage(r3, i3, j, 256);
    }
}

__global__ __launch_bounds__(NTHREADS, 8) void adaptive_topk_kernel(
    const float* __restrict__ in, int* __restrict__ out_idx, int* __restrict__ out_k)
{
    __shared__ uint32_t A32[NBINS / 2];   // 8 KB packed u16 bins: hist -> bases/cursors
    __shared__ uint32_t keys[KEYCAP];     // 6 KB u32 group-scatter keys
    __shared__ uint16_t outbuf[KSEL];     // 2 KB sorted indices staging
    __shared__ uint32_t glist[GLCAP];     // (n<<16)|base per active group
    __shared__ uint32_t wavetot[4];
    __shared__ float wsum[4], wsum2[4];
    __shared__ int sh_d1, sh_ng, sh_gp, sh_fb;

    const int row  = blockIdx.x;
    const int tid  = threadIdx.x;
    const int lane = tid & 63;
    const int wv   = tid >> 6;
    const float* __restrict__ rowp = in + (size_t)row * ROWLEN;
    int* __restrict__ orow = out_idx + (size_t)row * KSEL;
    const float4* r4 = (const float4*)rowp;

    const uint4 z0 = {0u, 0u, 0u, 0u};
    ((uint4*)A32)[tid] = z0;              // clear 2048 words (4096 u16 bins)
    ((uint4*)A32)[tid + 256] = z0;
    if (tid == 0) { sh_ng = 0; sh_gp = 0; sh_fb = 0; }
    __syncthreads();

    // ---- pass 1 over input: 12-bit histogram (packed u16) + moments.
    //      Values are NOT kept in registers (pressure!) - re-read later (L2-hot).
    float s = 0.0f, s2 = 0.0f;
#pragma unroll
    for (int it = 0; it < 4; ++it) {
        float4 v = r4[tid + 256 * it];
        s += (v.x + v.y) + (v.z + v.w);
        s2 = fmaf(v.x, v.x, fmaf(v.y, v.y, fmaf(v.z, v.z, fmaf(v.w, v.w, s2))));
        uint32_t bx = f2u_sortable(v.x) >> 20, by = f2u_sortable(v.y) >> 20;
        uint32_t bz = f2u_sortable(v.z) >> 20, bw = f2u_sortable(v.w) >> 20;
        atomicAdd(&A32[bx >> 1], (bx & 1) ? (1u << 16) : 1u);
        atomicAdd(&A32[by >> 1], (by & 1) ? (1u << 16) : 1u);
        atomicAdd(&A32[bz >> 1], (bz & 1) ? (1u << 16) : 1u);
        atomicAdd(&A32[bw >> 1], (bw & 1) ? (1u << 16) : 1u);
    }
    for (int off = 32; off > 0; off >>= 1) {
        s  += __shfl_down(s, off);
        s2 += __shfl_down(s2, off);
    }
    if (lane == 0) { wsum[wv] = s; wsum2[wv] = s2; }
    __syncthreads();                      // hist + wsum complete
    if (tid == 0) {
        double S  = (double)wsum[0] + wsum[1] + wsum[2] + wsum[3];
        double S2 = (double)wsum2[0] + wsum2[1] + wsum2[2] + wsum2[3];
        double var = (S2 - S * S / (double)ROWLEN) / (double)(ROWLEN - 1);
        float sp = log1pf(expf((float)var));
        float ka = 512.0f * (1.0f + 0.1f * sp);
        ka = fminf(fmaxf(ka, 128.0f), 1024.0f);
        out_k[row] = (int)ka;
    }

    // ---- suffix scan over 4096 bins; boundary digit d1; bases into A32 ----
    uint32_t hww[8];                       // my 16 bins, packed (static-indexed)
    {
        uint4 h0 = ((uint4*)A32)[2 * tid];
        uint4 h1 = ((uint4*)A32)[2 * tid + 1];
        hww[0] = h0.x; hww[1] = h0.y; hww[2] = h0.z; hww[3] = h0.w;
        hww[4] = h1.x; hww[5] = h1.y; hww[6] = h1.z; hww[7] = h1.w;
    }
    uint32_t csum = 0;
#pragma unroll
    for (int q = 0; q < 8; ++q) csum += (hww[q] & 0xFFFFu) + (hww[q] >> 16);
    uint32_t incl = csum;                 // inclusive suffix over chunk sums in wave
#pragma unroll
    for (int off = 1; off < 64; off <<= 1) {
        uint32_t t = __shfl_down(incl, off);
        if (lane + off < 64) incl += t;
    }
    if (lane == 0) wavetot[wv] = incl;
    __syncthreads();
    uint32_t later = 0;
    for (int w2 = wv + 1; w2 < 4; ++w2) later += wavetot[w2];
    const uint32_t R = (incl - csum) + later;   // elems in bins after my chunk
    {
        // word q holds bins 16*tid+2q (lo half) and 16*tid+2q+1 (hi half);
        // suffix-exclusive bases, bins descending; no arrays.
        uint32_t run = R;
#pragma unroll
        for (int q = 7; q >= 0; --q) {
            uint32_t h_hi = hww[q] >> 16, h_lo = hww[q] & 0xFFFFu;
            uint32_t base_hi = run;
            if (run < KSEL && KSEL <= run + h_hi) sh_d1 = 16 * tid + 2 * q + 1;
            run += h_hi;
            uint32_t base_lo = run;
            if (run < KSEL && KSEL <= run + h_lo) sh_d1 = 16 * tid + 2 * q;
            run += h_lo;
            A32[8 * tid + q] = (base_hi << 16) | base_lo;
        }
    }
    __syncthreads();                      // bases + sh_d1 visible

    const int d1 = sh_d1;

    // ---- group list build (bases by running subtraction; no arrays) ----
    {
        uint32_t run2 = R + csum;
#pragma unroll
        for (int b = 0; b < 16; ++b) {
            uint32_t n = (hww[b >> 1] >> ((b & 1) * 16)) & 0xFFFFu;
            run2 -= n;                    // = base of bin g
            int g = 16 * tid + b;
            if (g >= d1 && n > 0) {
                if (n > 256) sh_fb = 1;
                int p = atomicAdd(&sh_ng, 1);
                if (p < GLCAP) glist[p] = (n << 16) | run2;
                else sh_fb = 1;
            }
        }
    }
    // ---- pass 2 over input (L2-hot re-read): grouped scatter, u32 keys ----
#pragma unroll
    for (int it = 0; it < 4; ++it) {
        float4 v = r4[tid + 256 * it];
        const int idx0 = 4 * (tid + 256 * it);
#pragma unroll
        for (int e = 0; e < 4; ++e) {
            float f = (e == 0) ? v.x : (e == 1) ? v.y : (e == 2) ? v.z : v.w;
            uint32_t u = f2u_sortable(f);
            int g = (int)(u >> 20);
            if (g >= d1) {
                uint32_t old = atomicAdd(&A32[g >> 1], (g & 1) ? (1u << 16) : 1u);
                uint32_t pos = (g & 1) ? (old >> 16) : (old & 0xFFFFu);
                if (pos < KEYCAP)
                    keys[pos] = (u << 12) | (uint32_t)(ROWLEN - 1 - (idx0 + e));
            }
        }
    }
    __syncthreads();                      // keys + glist complete

    const int ng = min(sh_ng, GLCAP);
    if (!sh_fb) {
        // ---- per-group in-wave sorts -> LDS outbuf (no barriers) ----
        for (;;) {
            int gi = 0;
            if (lane == 0) gi = atomicAdd(&sh_gp, 1);
            gi = __shfl(gi, 0);
            if (gi >= ng) break;
            uint32_t ent = glist[gi];
            int base  = (int)(ent & 0xFFFFu);
            int n     = (int)(ent >> 16);
            int quota = min(n, KSEL - base);
            const int i0 = lane, i1 = lane + 64, i2 = lane + 128, i3 = lane + 192;
            if (n <= 64) {
                uint32_t r0 = (i0 < n) ? keys[base + i0] : 0u;
                sort64d(r0, lane);
                if (i0 < quota)
                    outbuf[base + i0] = (uint16_t)((ROWLEN - 1) - (int)(r0 & 0xFFFu));
            } else if (n <= 128) {
                uint32_t r0 = (i0 < n) ? keys[base + i0] : 0u;
                uint32_t r1 = (i1 < n) ? keys[base + i1] : 0u;
                sort128d(r0, r1, lane);
                if (i0 < quota)
                    outbuf[base + i0] = (uint16_t)((ROWLEN - 1) - (int)(r0 & 0xFFFu));
                if (i1 < quota)
                    outbuf[base + i1] = (uint16_t)((ROWLEN - 1) - (int)(r1 & 0xFFFu));
            } else {
                uint32_t r0 = (i0 < n) ? keys[base + i0] : 0u;
                uint32_t r1 = (i1 < n) ? keys[base + i1] : 0u;
                uint32_t r2 = (i2 < n) ? keys[base + i2] : 0u;
                uint32_t r3 = (i3 < n) ? keys[base + i3] : 0u;
                sort256d(r0, r1, r2, r3, lane);
                if (i0 < quota)
                    outbuf[base + i0] = (uint16_t)((ROWLEN - 1) - (int)(r0 & 0xFFFu));
                if (i1 < quota)
                    outbuf[base + i1] = (uint16_t)((ROWLEN - 1) - (int)(r1 & 0xFFFu));
                if (i2 < quota)
                    outbuf[base + i2] = (uint16_t)((ROWLEN - 1) - (int)(r2 & 0xFFFu));
                if (i3 < quota)
                    outbuf[base + i3] = (uint16_t)((ROWLEN - 1) - (int)(r3 & 0xFFFu));
            }
        }
        __syncthreads();                  // outbuf complete
        // ---- single coalesced row store: ushort4 (LDS) -> int4 (global) ----
        ushort4 t4 = ((const ushort4*)outbuf)[tid];
        int4 ov = { (int)t4.x, (int)t4.y, (int)t4.z, (int)t4.w };
        ((int4*)orow)[tid] = ov;
    } else {
        // ---- exact cooperative fallback (statistically never taken) ----
        if (tid < 64) {
            u64 prev = ~0ull;
            for (int r = 0; r < KSEL; ++r) {
                u64 best = 0;
                for (int c = lane; c < ROWLEN; c += 64) {
                    u64 K = ((u64)f2u_sortable(rowp[c]) << 12) | (u64)(ROWLEN - 1 - c);
                    if (K < prev && K > best) best = K;
                }
                for (int off = 32; off > 0; off >>= 1) {
                    u64 o = __shfl_xor(best, off, 64);
                    best = best > o ? best : o;
                }
                if (lane == 0) orow[r] = (ROWLEN - 1) - (int)(best & 0xFFFu);
                prev = best;
            }
        }
    }
}

extern "C" void kernel_launch(void* const* d_in, const int* in_sizes, int n_in,
                              void* d_out, int out_size, void* d_ws, size_t ws_size,
                              hipStream_t stream) {
    const float* in = (const float*)d_in[0];
    const int B = in_sizes[0] / (ROWLEN * ROWLEN);   // 4
    const int nrows = B * ROWLEN;                    // 16384
    int* out = (int*)d_out;
    int* out_idx = out;                              // B*L*KSEL
    int* out_k   = out + (size_t)nrows * KSEL;       // B*L
    adaptive_topk_kernel<<<dim3(nrows), dim3(NTHREADS), 0, stream>>>(in, out_idx, out_k);
}